// Round 10
// baseline (535.851 us; speedup 1.0000x reference)
//
#include <hip/hip_runtime.h>
#include <hip/hip_bf16.h>

#define N_FULL 200000
#define N_SUB  80000
#define E_NUM  800000
#define IN_DIM 128
#define HD     128
#define LMAX   5

#define NB_SCAN ((N_SUB + 255) / 256)   // 313
#define NB_E (E_NUM / 256)              // 3125
#define WCOMB_BLKS 128
#define CSR_STRIDE 64

// ---------------- fill fixed-stride CSR + level init + wcomb ----------------
// csr64[d*64 + p] = src, p = atomicAdd(cnt[d]) (deg stays in cnt).
// Wc1 = W_l@W_in, Wc2 = W_r@W_in, bc = (W_l+W_r)@b_in + b_l

__global__ __launch_bounds__(256) void fill_wcomb(
    const int* __restrict__ esrc, const int* __restrict__ edst,
    int* __restrict__ cnt, int* __restrict__ csr, int* __restrict__ level,
    const float* __restrict__ W_l, const float* __restrict__ W_r,
    const float* __restrict__ W_in, const float* __restrict__ b_in,
    const float* __restrict__ b_l,
    float* __restrict__ Wc1, float* __restrict__ Wc2, float* __restrict__ bc) {
    int b = blockIdx.x;
    int t = threadIdx.x;
    if (b < NB_E) {
        if (b < NB_SCAN) {
            int i = b * 256 + t;
            if (i < N_SUB) level[i] = (i < 2) ? 0 : 7;
        }
        int i = b * 256 + t;
        int d = edst[i];
        int p = atomicAdd(&cnt[d], 1);
        if (p < CSR_STRIDE) csr[d * CSR_STRIDE + p] = esrc[i];
    } else {
        __shared__ float sf[256];
        int f = b - NB_E;                    // 0..127
        if (t < 128) sf[t] = W_l[f * 128 + t];
        else sf[t] = W_r[f * 128 + (t - 128)];
        __syncthreads();
        int c = t & 127, p = t >> 7;
        const float* wrow = p ? (sf + 128) : sf;
        float acc = 0.f;
#pragma unroll 8
        for (int j = 0; j < 128; ++j)
            acc = fmaf(wrow[j], W_in[j * 128 + c], acc);
        (p ? Wc2 : Wc1)[f * 128 + c] = acc;
        if (t < 64) {
            float pa = (sf[t] + sf[128 + t]) * b_in[t] +
                       (sf[t + 64] + sf[192 + t]) * b_in[t + 64];
            for (int off = 32; off; off >>= 1) pa += __shfl_down(pa, off);
            if (t == 0) bc[f] = pa + b_l[f];
        }
    }
}

// ---------------- reverse BFS via CSR64, frontier-sparse node-parallel ----------------

__global__ void bfs_csr(const int* __restrict__ cnt, const int* __restrict__ csr,
                        int* __restrict__ level, int t) {
    int i = blockIdx.x * blockDim.x + threadIdx.x;
    if (i >= N_SUB) return;
    if (level[i] != t) return;
    int beg = i * CSR_STRIDE, end = beg + cnt[i];
    for (int j = beg; j < end; ++j) {
        int u = csr[j];
        if (level[u] > t + 1) level[u] = t + 1;
    }
}

// ---------------- level compaction (multi-block, LDS atomics only) ----------------

__global__ __launch_bounds__(256) void hist_levels(const int* __restrict__ level,
                                                   int* __restrict__ bhist) {
    __shared__ int h[8];
    int t = threadIdx.x;
    if (t < 8) h[t] = 0;
    __syncthreads();
    int i = blockIdx.x * 256 + t;
    if (i < N_SUB) {
        int l = level[i];
        if (l > 5) l = 6;
        atomicAdd(&h[l], 1);
    }
    __syncthreads();
    if (t < 8) bhist[blockIdx.x * 8 + t] = h[t];
}

__global__ void scan_hist(int* __restrict__ bhist, int* __restrict__ base,
                          int* __restrict__ cum) {
    __shared__ int tot[8];
    int t = threadIdx.x;
    if (t < 8) {
        int acc = 0;
        for (int b = 0; b < NB_SCAN; ++b) {
            int v = bhist[b * 8 + t];
            bhist[b * 8 + t] = acc;
            acc += v;
        }
        tot[t] = acc;
    }
    __syncthreads();
    if (t == 0) {
        int acc = 0;
        for (int l = 0; l <= 5; ++l) {
            base[l] = acc;
            acc += tot[l];
            cum[l] = acc;
        }
    }
}

__global__ __launch_bounds__(256) void emit_order(const int* __restrict__ level,
                                                  const int* __restrict__ bhist,
                                                  const int* __restrict__ base,
                                                  int* __restrict__ order) {
    __shared__ int woff[4][8];
    int t = threadIdx.x;
    int lane = t & 63, wv = t >> 6;
    int i = blockIdx.x * 256 + t;
    int l = 7;
    if (i < N_SUB) {
        l = level[i];
        if (l > 5) l = 6;
    }
    unsigned long long mybal = 0;
#pragma unroll
    for (int q = 0; q < 8; ++q) {
        unsigned long long b = __ballot(l == q);
        if (q == l) mybal = b;
        if (lane == 0) woff[wv][q] = (int)__popcll(b);
    }
    int inrank = (int)__popcll(mybal & ((1ull << lane) - 1ull));
    __syncthreads();
    if (t < 8) {
        int acc = 0;
        for (int w2 = 0; w2 < 4; ++w2) {
            int c = woff[w2][t];
            woff[w2][t] = acc;
            acc += c;
        }
    }
    __syncthreads();
    if (i < N_SUB && l <= 5) {
        int pos = base[l] + bhist[blockIdx.x * 8 + l] + woff[wv][l] + inrank;
        order[pos] = i;
    }
}

// ---------------- mean aggregation over node list (high-occupancy) ----------------

__device__ void dev_aggregate(
    const float* __restrict__ H, float* __restrict__ Out,
    const int* __restrict__ cnt, const int* __restrict__ csr,
    const int* __restrict__ order, int M, const int* __restrict__ srcmap,
    int bid0, int nb) {
    int ngroups = (M + 3) >> 2;
    int wid = threadIdx.x >> 6, lane = threadIdx.x & 63;
    for (int g = bid0; g < ngroups; g += nb) {
        int ni = g * 4 + wid;
        if (ni >= M) continue;
        int node = order[ni];
        int deg = cnt[node];
        int beg = node * CSR_STRIDE, end = beg + deg;
        float ax = 0.f, ay = 0.f, bx = 0.f, by = 0.f;
        int j = beg;
        for (; j + 1 < end; j += 2) {
            int s0 = csr[j], s1 = csr[j + 1];
            int r0 = srcmap ? srcmap[s0] : s0;
            int r1 = srcmap ? srcmap[s1] : s1;
            float2 v0 = *(const float2*)(H + (size_t)r0 * HD + lane * 2);
            float2 v1 = *(const float2*)(H + (size_t)r1 * HD + lane * 2);
            ax += v0.x; ay += v0.y;
            bx += v1.x; by += v1.y;
        }
        if (j < end) {
            int s0 = csr[j];
            int r0 = srcmap ? srcmap[s0] : s0;
            float2 v0 = *(const float2*)(H + (size_t)r0 * HD + lane * 2);
            ax += v0.x; ay += v0.y;
        }
        float inv = 1.0f / (float)(deg > 1 ? deg : 1);
        *(float2*)(Out + (size_t)node * HD + lane * 2) =
            make_float2((ax + bx) * inv, (ay + by) * inv);
    }
}

__global__ __launch_bounds__(256) void aggregate_list(
    const float* __restrict__ H, float* __restrict__ Out,
    const int* __restrict__ cnt, const int* __restrict__ csr,
    const int* __restrict__ order, const int* __restrict__ cum, int lvl,
    const int* __restrict__ srcmap) {
    dev_aggregate(H, Out, cnt, csr, order, cum[lvl], srcmap,
                  blockIdx.x, gridDim.x);
}

// ---------------- head MLP on nodes 0,1 (device fn, 256 threads) ----------------

__device__ void dev_head(
    const float* __restrict__ H,
    const float* __restrict__ W_e1, const float* __restrict__ b_e1,
    const float* __restrict__ W_e2, const float* __restrict__ b_e2,
    const float* __restrict__ W_h1, const float* __restrict__ b_h1,
    const float* __restrict__ W_h2, const float* __restrict__ b_h2,
    float* __restrict__ head_out, int kidx) {

    __shared__ float feat[384];
    __shared__ float rowo[128];
    __shared__ float sc_sh;
    int t = threadIdx.x, lane = t & 63, wv = t >> 6;

    __syncthreads();
    if (t < 128) {
        float a = H[t], b = H[128 + t];
        feat[t] = a;
        feat[128 + t] = b;
        feat[256 + t] = a * b;
    }
    __syncthreads();

    for (int r = wv; r < 128; r += 4) {
        const float* wr = W_e1 + r * 384;
        float acc = 0.f;
#pragma unroll
        for (int j = 0; j < 6; ++j)
            acc += feat[lane + 64 * j] * wr[lane + 64 * j];
        for (int off = 32; off; off >>= 1) acc += __shfl_down(acc, off);
        if (lane == 0) rowo[r] = fmaxf(acc + b_e1[r], 0.f) * W_e2[r];
    }
    __syncthreads();
    if (wv == 0) {
        float v = rowo[lane] + rowo[lane + 64];
        for (int off = 32; off; off >>= 1) v += __shfl_down(v, off);
        if (lane == 0) sc_sh = v + b_e2[0];
    }
    __syncthreads();
    float score = sc_sh;

    for (int r = wv; r < 64; r += 4) {
        const float* wh = W_h1 + r * 257;
        float acc = 0.f;
#pragma unroll
        for (int j = 0; j < 4; ++j)
            acc += feat[lane + 64 * j] * wh[lane + 64 * j];
        if (lane == 0) acc += score * wh[256];
        for (int off = 32; off; off >>= 1) acc += __shfl_down(acc, off);
        if (lane == 0) rowo[r] = fmaxf(acc + b_h1[r], 0.f) * W_h2[r];
    }
    __syncthreads();
    if (wv == 0) {
        float v = rowo[lane];
        for (int off = 32; off; off >>= 1) v += __shfl_down(v, off);
        if (lane == 0) {
            float p = 1.f / (1.f + expf(-(v + b_h2[0])));
            head_out[kidx * 2 + 0] = score;
            head_out[kidx * 2 + 1] = p;
        }
    }
    __syncthreads();
}

// ---------------- fp32 tiled GEMM: 128x128 block tile, 8x8 thread tile ----------------
// Out[nr][:] = relu( A1[gA(nr)] @ W1.T + A2[gB(nr)] @ W2.T + bias ), nr = order[row]
// thread (tx,ty): rows {ty*4+i, 64+ty*4+i}, cols {tx*4+j, 64+tx*4+j}

#define GBM 128
#define GBK 32

__device__ void dev_gemm(
    const float* __restrict__ A1, const float* __restrict__ A2,
    const float* __restrict__ W1, const float* __restrict__ W2,
    const float* __restrict__ bias, float* __restrict__ Out,
    const int* __restrict__ order, const int* __restrict__ gatherA,
    const int* __restrict__ gatherB, int M, int bid0, int nb,
    const float* __restrict__ W_e1, const float* __restrict__ b_e1,
    const float* __restrict__ W_e2, const float* __restrict__ b_e2,
    const float* __restrict__ W_h1, const float* __restrict__ b_h1,
    const float* __restrict__ W_h2, const float* __restrict__ b_h2,
    float* __restrict__ head_out, int head_kidx) {

    __shared__ __align__(16) float As[GBK][132];
    __shared__ __align__(16) float Ws[GBK][132];

    int ntiles = (M + GBM - 1) / GBM;
    int tid = threadIdx.x;
    int tx = tid & 15, ty = tid >> 4;
    int r0 = ty * 4;
    int c0 = tx * 4;

    for (int tile = bid0; tile < ntiles; tile += nb) {
        int row0 = tile * GBM;

        float acc[2][2][4][4];
#pragma unroll
        for (int p = 0; p < 2; ++p)
#pragma unroll
            for (int q = 0; q < 2; ++q)
#pragma unroll
                for (int i = 0; i < 4; ++i)
#pragma unroll
                    for (int j = 0; j < 4; ++j) acc[p][q][i][j] = 0.f;

        for (int ch = 0; ch < 8; ++ch) {
            const float* Asrc = (ch < 4) ? A1 : A2;
            const float* Wsrc = (ch < 4) ? W1 : W2;
            const int* gmap = (ch < 4) ? gatherA : gatherB;
            int kbase = (ch & 3) * GBK;

            // stage A: 128 rows x 32 k; m = idx&127 -> conflict-free LDS writes
#pragma unroll
            for (int it = 0; it < 4; ++it) {
                int idx = tid + it * 256;
                int m = idx & 127, kq = idx >> 7;
                int row = row0 + m;
                float4 v = make_float4(0.f, 0.f, 0.f, 0.f);
                if (row < M) {
                    int nr = order[row];
                    int ar = gmap ? gmap[nr] : nr;
                    v = *(const float4*)(Asrc + (size_t)ar * 128 + kbase + kq * 4);
                }
                As[kq * 4 + 0][m] = v.x;
                As[kq * 4 + 1][m] = v.y;
                As[kq * 4 + 2][m] = v.z;
                As[kq * 4 + 3][m] = v.w;
            }
            // stage W: 128 n x 32 k; n = idx>>3 -> coalesced global reads
#pragma unroll
            for (int it = 0; it < 4; ++it) {
                int idx = tid + it * 256;
                int n = idx >> 3, kq = idx & 7;
                float4 v = *(const float4*)(Wsrc + n * 128 + kbase + kq * 4);
                Ws[kq * 4 + 0][n] = v.x;
                Ws[kq * 4 + 1][n] = v.y;
                Ws[kq * 4 + 2][n] = v.z;
                Ws[kq * 4 + 3][n] = v.w;
            }
            __syncthreads();

#pragma unroll
            for (int kk = 0; kk < GBK; ++kk) {
                float4 a0 = *(const float4*)&As[kk][r0];
                float4 a1 = *(const float4*)&As[kk][r0 + 64];
                float4 w0 = *(const float4*)&Ws[kk][c0];
                float4 w1 = *(const float4*)&Ws[kk][c0 + 64];
                float av[2][4] = {{a0.x, a0.y, a0.z, a0.w}, {a1.x, a1.y, a1.z, a1.w}};
                float wv[2][4] = {{w0.x, w0.y, w0.z, w0.w}, {w1.x, w1.y, w1.z, w1.w}};
#pragma unroll
                for (int p = 0; p < 2; ++p)
#pragma unroll
                    for (int q = 0; q < 2; ++q)
#pragma unroll
                        for (int i = 0; i < 4; ++i)
#pragma unroll
                            for (int j = 0; j < 4; ++j)
                                acc[p][q][i][j] = fmaf(av[p][i], wv[q][j], acc[p][q][i][j]);
            }
            __syncthreads();
        }

#pragma unroll
        for (int p = 0; p < 2; ++p) {
#pragma unroll
            for (int i = 0; i < 4; ++i) {
                int row = row0 + p * 64 + r0 + i;
                if (row >= M) continue;
                int nr = order[row];
                float4 o0, o1;
                o0.x = fmaxf(acc[p][0][i][0] + bias[c0 + 0], 0.f);
                o0.y = fmaxf(acc[p][0][i][1] + bias[c0 + 1], 0.f);
                o0.z = fmaxf(acc[p][0][i][2] + bias[c0 + 2], 0.f);
                o0.w = fmaxf(acc[p][0][i][3] + bias[c0 + 3], 0.f);
                o1.x = fmaxf(acc[p][1][i][0] + bias[c0 + 64], 0.f);
                o1.y = fmaxf(acc[p][1][i][1] + bias[c0 + 65], 0.f);
                o1.z = fmaxf(acc[p][1][i][2] + bias[c0 + 66], 0.f);
                o1.w = fmaxf(acc[p][1][i][3] + bias[c0 + 67], 0.f);
                *(float4*)(Out + (size_t)nr * 128 + c0) = o0;
                *(float4*)(Out + (size_t)nr * 128 + c0 + 64) = o1;
            }
        }

        // fused head: tile 0 computed rows 0,1 (= nodes 0,1) fully
        if (tile == 0 && head_kidx >= 0) {
            dev_head(Out, W_e1, b_e1, W_e2, b_e2, W_h1, b_h1, W_h2, b_h2,
                     head_out, head_kidx);
        }
    }
}

__global__ __launch_bounds__(256) void gemm_list(
    const float* __restrict__ A1, const float* __restrict__ A2,
    const float* __restrict__ W1, const float* __restrict__ W2,
    const float* __restrict__ bias, float* __restrict__ Out,
    const int* __restrict__ order, const int* __restrict__ gatherA,
    const int* __restrict__ gatherB, const int* __restrict__ cum, int lvl,
    const float* __restrict__ W_e1, const float* __restrict__ b_e1,
    const float* __restrict__ W_e2, const float* __restrict__ b_e2,
    const float* __restrict__ W_h1, const float* __restrict__ b_h1,
    const float* __restrict__ W_h2, const float* __restrict__ b_h2,
    float* __restrict__ head_out, int head_kidx) {
    dev_gemm(A1, A2, W1, W2, bias, Out, order, gatherA, gatherB, cum[lvl],
             blockIdx.x, gridDim.x,
             W_e1, b_e1, W_e2, b_e2, W_h1, b_h1, W_h2, b_h2,
             head_out, head_kidx);
}

// ---------------- tail: steps 4,5 (~22 and 2 nodes) + heads + finalize ----------------

__global__ __launch_bounds__(256) void tail_small(
    float* __restrict__ HA, float* __restrict__ HB,
    const int* __restrict__ order, const int* __restrict__ cnt,
    const int* __restrict__ csr, const int* __restrict__ cum,
    const float* __restrict__ W_l, const float* __restrict__ b_l,
    const float* __restrict__ W_r,
    const float* __restrict__ W_e1, const float* __restrict__ b_e1,
    const float* __restrict__ W_e2, const float* __restrict__ b_e2,
    const float* __restrict__ W_h1, const float* __restrict__ b_h1,
    const float* __restrict__ W_h2, const float* __restrict__ b_h2,
    float* __restrict__ head_out, float* __restrict__ out) {

    // k=4 on C_1
    dev_aggregate(HA, HB, cnt, csr, order, cum[1], nullptr, 0, 1);
    __syncthreads();
    dev_gemm(HB, HA, W_l, W_r, b_l, HA, order, nullptr, nullptr, cum[1], 0, 1,
             W_e1, b_e1, W_e2, b_e2, W_h1, b_h1, W_h2, b_h2, head_out, 3);
    __syncthreads();
    // k=5 on C_0
    dev_aggregate(HA, HB, cnt, csr, order, cum[0], nullptr, 0, 1);
    __syncthreads();
    dev_gemm(HB, HA, W_l, W_r, b_l, HA, order, nullptr, nullptr, cum[0], 0, 1,
             W_e1, b_e1, W_e2, b_e2, W_h1, b_h1, W_h2, b_h2, head_out, 4);
    __syncthreads();

    if (threadIdx.x == 0) {
        float a[LMAX];
        float p_not = 1.f, s = 0.f;
        for (int k = 0; k < LMAX; ++k) {
            float p = head_out[2 * k + 1];
            a[k] = p * p_not;
            p_not *= (1.f - p);
            s += a[k];
        }
        float inv = 1.f / (s + 1e-8f);
        float fs = 0.f, ed = 0.f;
        for (int k = 0; k < LMAX; ++k) {
            float al = a[k] * inv;
            out[2 + k] = al;
            fs += al * head_out[2 * k];
            ed += al * (float)(k + 1);
        }
        out[0] = fs;
        out[1] = ed;
    }
}

// ---------------- launch ----------------

extern "C" void kernel_launch(void* const* d_in, const int* in_sizes, int n_in,
                              void* d_out, int out_size, void* d_ws, size_t ws_size,
                              hipStream_t stream) {
    const float* x_full = (const float*)d_in[0];
    const float* W_in  = (const float*)d_in[1];
    const float* b_in  = (const float*)d_in[2];
    const float* W_l   = (const float*)d_in[3];
    const float* b_l   = (const float*)d_in[4];
    const float* W_r   = (const float*)d_in[5];
    const float* W_e1  = (const float*)d_in[6];
    const float* b_e1  = (const float*)d_in[7];
    const float* W_e2  = (const float*)d_in[8];
    const float* b_e2  = (const float*)d_in[9];
    const float* W_h1  = (const float*)d_in[10];
    const float* b_h1  = (const float*)d_in[11];
    const float* W_h2  = (const float*)d_in[12];
    const float* b_h2  = (const float*)d_in[13];
    const int* subset  = (const int*)d_in[14];
    const int* edge    = (const int*)d_in[15];
    const int* esrc = edge;
    const int* edst = edge + E_NUM;

    // workspace carve-up
    char* w = (char*)d_ws;
    float* HA = (float*)w;      w += (size_t)N_SUB * HD * 4;               // 41 MB
    float* HB = (float*)w;      w += (size_t)N_SUB * HD * 4;               // 41 MB
    int* cnt = (int*)w;         w += (size_t)N_SUB * 4;
    int* csr = (int*)w;         w += (size_t)N_SUB * CSR_STRIDE * 4;       // 20.5 MB
    int* level = (int*)w;       w += (size_t)N_SUB * 4;
    int* order = (int*)w;       w += (size_t)N_SUB * 4;
    int* bhist = (int*)w;       w += (size_t)(NB_SCAN + 1) * 8 * 4;
    int* lvlbase = (int*)w;     w += 64;
    int* cum = (int*)w;         w += 64;
    float* Wc1 = (float*)w;     w += 128 * 128 * 4;
    float* Wc2 = (float*)w;     w += 128 * 128 * 4;
    float* bc = (float*)w;      w += 512;
    float* head_out = (float*)w; w += 256;

    // prep: CSR64 fill (+level init, +wcomb)
    hipMemsetAsync(cnt, 0, (size_t)N_SUB * 4, stream);
    fill_wcomb<<<NB_E + WCOMB_BLKS, 256, 0, stream>>>(
        esrc, edst, cnt, csr, level, W_l, W_r, W_in, b_in, b_l, Wc1, Wc2, bc);

    // reverse BFS levels 1..4 (frontier-sparse, multi-block)
    for (int t = 0; t < 4; ++t)
        bfs_csr<<<NB_SCAN, 256, 0, stream>>>(cnt, csr, level, t);

    // level compaction
    hist_levels<<<NB_SCAN, 256, 0, stream>>>(level, bhist);
    scan_hist<<<1, 64, 0, stream>>>(bhist, lvlbase, cum);
    emit_order<<<NB_SCAN, 256, 0, stream>>>(level, bhist, lvlbase, order);

    // k=1 on C_4 (linearity: aggregate raw x, combined weights), head kidx=0
    aggregate_list<<<2048, 256, 0, stream>>>(
        x_full, HB, cnt, csr, order, cum, 4, subset);
    gemm_list<<<256, 256, 0, stream>>>(
        HB, x_full, Wc1, Wc2, bc, HA, order, nullptr, subset, cum, 4,
        W_e1, b_e1, W_e2, b_e2, W_h1, b_h1, W_h2, b_h2, head_out, 0);

    // k=2 on C_3
    aggregate_list<<<64, 256, 0, stream>>>(
        HA, HB, cnt, csr, order, cum, 3, nullptr);
    gemm_list<<<32, 256, 0, stream>>>(
        HB, HA, W_l, W_r, b_l, HA, order, nullptr, nullptr, cum, 3,
        W_e1, b_e1, W_e2, b_e2, W_h1, b_h1, W_h2, b_h2, head_out, 1);

    // k=3 on C_2
    aggregate_list<<<16, 256, 0, stream>>>(
        HA, HB, cnt, csr, order, cum, 2, nullptr);
    gemm_list<<<2, 256, 0, stream>>>(
        HB, HA, W_l, W_r, b_l, HA, order, nullptr, nullptr, cum, 2,
        W_e1, b_e1, W_e2, b_e2, W_h1, b_h1, W_h2, b_h2, head_out, 2);

    // k=4,5 + finalize
    tail_small<<<1, 256, 0, stream>>>(
        HA, HB, order, cnt, csr, cum,
        W_l, b_l, W_r, W_e1, b_e1, W_e2, b_e2, W_h1, b_h1, W_h2, b_h2,
        head_out, (float*)d_out);
}

// Round 11
// 517.149 us; speedup vs baseline: 1.0362x; 1.0362x over previous
//
#include <hip/hip_runtime.h>
#include <hip/hip_bf16.h>

#define N_FULL 200000
#define N_SUB  80000
#define E_NUM  800000
#define IN_DIM 128
#define HD     128
#define LMAX   5

#define NB_SCAN ((N_SUB + 255) / 256)   // 313
#define NB_E (E_NUM / 256)              // 3125
#define WCOMB_BLKS 128
#define CSR_STRIDE 64

// ---------------- fill fixed-stride CSR + level init + wcomb ----------------
// csr64[d*64 + p] = src, p = atomicAdd(cnt[d]) (deg stays in cnt).
// Wc1 = W_l@W_in, Wc2 = W_r@W_in, bc = (W_l+W_r)@b_in + b_l

__global__ __launch_bounds__(256) void fill_wcomb(
    const int* __restrict__ esrc, const int* __restrict__ edst,
    int* __restrict__ cnt, int* __restrict__ csr, int* __restrict__ level,
    const float* __restrict__ W_l, const float* __restrict__ W_r,
    const float* __restrict__ W_in, const float* __restrict__ b_in,
    const float* __restrict__ b_l,
    float* __restrict__ Wc1, float* __restrict__ Wc2, float* __restrict__ bc) {
    int b = blockIdx.x;
    int t = threadIdx.x;
    if (b < NB_E) {
        if (b < NB_SCAN) {
            int i = b * 256 + t;
            if (i < N_SUB) level[i] = (i < 2) ? 0 : 7;
        }
        int i = b * 256 + t;
        int d = edst[i];
        int p = atomicAdd(&cnt[d], 1);
        if (p < CSR_STRIDE) csr[d * CSR_STRIDE + p] = esrc[i];
    } else {
        __shared__ float sf[256];
        int f = b - NB_E;                    // 0..127
        if (t < 128) sf[t] = W_l[f * 128 + t];
        else sf[t] = W_r[f * 128 + (t - 128)];
        __syncthreads();
        int c = t & 127, p = t >> 7;
        const float* wrow = p ? (sf + 128) : sf;
        float acc = 0.f;
#pragma unroll 8
        for (int j = 0; j < 128; ++j)
            acc = fmaf(wrow[j], W_in[j * 128 + c], acc);
        (p ? Wc2 : Wc1)[f * 128 + c] = acc;
        if (t < 64) {
            float pa = (sf[t] + sf[128 + t]) * b_in[t] +
                       (sf[t + 64] + sf[192 + t]) * b_in[t + 64];
            for (int off = 32; off; off >>= 1) pa += __shfl_down(pa, off);
            if (t == 0) bc[f] = pa + b_l[f];
        }
    }
}

// ---------------- reverse BFS via CSR64, frontier-sparse node-parallel ----------------

__global__ void bfs_csr(const int* __restrict__ cnt, const int* __restrict__ csr,
                        int* __restrict__ level, int t) {
    int i = blockIdx.x * blockDim.x + threadIdx.x;
    if (i >= N_SUB) return;
    if (level[i] != t) return;
    int beg = i * CSR_STRIDE, end = beg + cnt[i];
    for (int j = beg; j < end; ++j) {
        int u = csr[j];
        if (level[u] > t + 1) level[u] = t + 1;
    }
}

// ---------------- level compaction (multi-block, LDS atomics only) ----------------

__global__ __launch_bounds__(256) void hist_levels(const int* __restrict__ level,
                                                   int* __restrict__ bhist) {
    __shared__ int h[8];
    int t = threadIdx.x;
    if (t < 8) h[t] = 0;
    __syncthreads();
    int i = blockIdx.x * 256 + t;
    if (i < N_SUB) {
        int l = level[i];
        if (l > 5) l = 6;
        atomicAdd(&h[l], 1);
    }
    __syncthreads();
    if (t < 8) bhist[blockIdx.x * 8 + t] = h[t];
}

__global__ void scan_hist(int* __restrict__ bhist, int* __restrict__ base,
                          int* __restrict__ cum) {
    __shared__ int tot[8];
    int t = threadIdx.x;
    if (t < 8) {
        int acc = 0;
        for (int b = 0; b < NB_SCAN; ++b) {
            int v = bhist[b * 8 + t];
            bhist[b * 8 + t] = acc;
            acc += v;
        }
        tot[t] = acc;
    }
    __syncthreads();
    if (t == 0) {
        int acc = 0;
        for (int l = 0; l <= 5; ++l) {
            base[l] = acc;
            acc += tot[l];
            cum[l] = acc;
        }
    }
}

__global__ __launch_bounds__(256) void emit_order(const int* __restrict__ level,
                                                  const int* __restrict__ bhist,
                                                  const int* __restrict__ base,
                                                  int* __restrict__ order) {
    __shared__ int woff[4][8];
    int t = threadIdx.x;
    int lane = t & 63, wv = t >> 6;
    int i = blockIdx.x * 256 + t;
    int l = 7;
    if (i < N_SUB) {
        l = level[i];
        if (l > 5) l = 6;
    }
    unsigned long long mybal = 0;
#pragma unroll
    for (int q = 0; q < 8; ++q) {
        unsigned long long b = __ballot(l == q);
        if (q == l) mybal = b;
        if (lane == 0) woff[wv][q] = (int)__popcll(b);
    }
    int inrank = (int)__popcll(mybal & ((1ull << lane) - 1ull));
    __syncthreads();
    if (t < 8) {
        int acc = 0;
        for (int w2 = 0; w2 < 4; ++w2) {
            int c = woff[w2][t];
            woff[w2][t] = acc;
            acc += c;
        }
    }
    __syncthreads();
    if (i < N_SUB && l <= 5) {
        int pos = base[l] + bhist[blockIdx.x * 8 + l] + woff[wv][l] + inrank;
        order[pos] = i;
    }
}

// ---------------- mean aggregation over node list (high-occupancy) ----------------

__global__ __launch_bounds__(256) void aggregate_list(
    const float* __restrict__ H, float* __restrict__ Out,
    const int* __restrict__ cnt, const int* __restrict__ csr,
    const int* __restrict__ order, const int* __restrict__ cum, int lvl,
    const int* __restrict__ srcmap) {
    int M = cum[lvl];
    int ngroups = (M + 3) >> 2;
    int wid = threadIdx.x >> 6, lane = threadIdx.x & 63;
    for (int g = blockIdx.x; g < ngroups; g += gridDim.x) {
        int ni = g * 4 + wid;
        if (ni >= M) continue;
        int node = order[ni];
        int deg = cnt[node];
        int beg = node * CSR_STRIDE, end = beg + deg;
        float ax = 0.f, ay = 0.f, bx = 0.f, by = 0.f;
        int j = beg;
        for (; j + 1 < end; j += 2) {
            int s0 = csr[j], s1 = csr[j + 1];
            int r0 = srcmap ? srcmap[s0] : s0;
            int r1 = srcmap ? srcmap[s1] : s1;
            float2 v0 = *(const float2*)(H + (size_t)r0 * HD + lane * 2);
            float2 v1 = *(const float2*)(H + (size_t)r1 * HD + lane * 2);
            ax += v0.x; ay += v0.y;
            bx += v1.x; by += v1.y;
        }
        if (j < end) {
            int s0 = csr[j];
            int r0 = srcmap ? srcmap[s0] : s0;
            float2 v0 = *(const float2*)(H + (size_t)r0 * HD + lane * 2);
            ax += v0.x; ay += v0.y;
        }
        float inv = 1.0f / (float)(deg > 1 ? deg : 1);
        *(float2*)(Out + (size_t)node * HD + lane * 2) =
            make_float2((ax + bx) * inv, (ay + by) * inv);
    }
}

// ---------------- head MLP on nodes 0,1 (device fn, 256 threads) ----------------

__device__ void dev_head(
    const float* __restrict__ H,
    const float* __restrict__ W_e1, const float* __restrict__ b_e1,
    const float* __restrict__ W_e2, const float* __restrict__ b_e2,
    const float* __restrict__ W_h1, const float* __restrict__ b_h1,
    const float* __restrict__ W_h2, const float* __restrict__ b_h2,
    float* __restrict__ head_out, int kidx) {

    __shared__ float feat[384];
    __shared__ float rowo[128];
    __shared__ float sc_sh;
    int t = threadIdx.x, lane = t & 63, wv = t >> 6;

    __syncthreads();
    if (t < 128) {
        float a = H[t], b = H[128 + t];
        feat[t] = a;
        feat[128 + t] = b;
        feat[256 + t] = a * b;
    }
    __syncthreads();

    for (int r = wv; r < 128; r += 4) {
        const float* wr = W_e1 + r * 384;
        float acc = 0.f;
#pragma unroll
        for (int j = 0; j < 6; ++j)
            acc += feat[lane + 64 * j] * wr[lane + 64 * j];
        for (int off = 32; off; off >>= 1) acc += __shfl_down(acc, off);
        if (lane == 0) rowo[r] = fmaxf(acc + b_e1[r], 0.f) * W_e2[r];
    }
    __syncthreads();
    if (wv == 0) {
        float v = rowo[lane] + rowo[lane + 64];
        for (int off = 32; off; off >>= 1) v += __shfl_down(v, off);
        if (lane == 0) sc_sh = v + b_e2[0];
    }
    __syncthreads();
    float score = sc_sh;

    for (int r = wv; r < 64; r += 4) {
        const float* wh = W_h1 + r * 257;
        float acc = 0.f;
#pragma unroll
        for (int j = 0; j < 4; ++j)
            acc += feat[lane + 64 * j] * wh[lane + 64 * j];
        if (lane == 0) acc += score * wh[256];
        for (int off = 32; off; off >>= 1) acc += __shfl_down(acc, off);
        if (lane == 0) rowo[r] = fmaxf(acc + b_h1[r], 0.f) * W_h2[r];
    }
    __syncthreads();
    if (wv == 0) {
        float v = rowo[lane];
        for (int off = 32; off; off >>= 1) v += __shfl_down(v, off);
        if (lane == 0) {
            float p = 1.f / (1.f + expf(-(v + b_h2[0])));
            head_out[kidx * 2 + 0] = score;
            head_out[kidx * 2 + 1] = p;
        }
    }
    __syncthreads();
}

// ---------------- fp32 tiled GEMM: 128x128 block tile, 8x8 thread tile ----------------
// Out[nr][:] = relu( A1[gA(nr)] @ W1.T + A2[gB(nr)] @ W2.T + bias ), nr = order[row]

#define GBM 128
#define GBK 32

__global__ __launch_bounds__(256) void gemm_list(
    const float* __restrict__ A1, const float* __restrict__ A2,
    const float* __restrict__ W1, const float* __restrict__ W2,
    const float* __restrict__ bias, float* __restrict__ Out,
    const int* __restrict__ order, const int* __restrict__ gatherA,
    const int* __restrict__ gatherB, const int* __restrict__ cum, int lvl,
    const float* __restrict__ W_e1, const float* __restrict__ b_e1,
    const float* __restrict__ W_e2, const float* __restrict__ b_e2,
    const float* __restrict__ W_h1, const float* __restrict__ b_h1,
    const float* __restrict__ W_h2, const float* __restrict__ b_h2,
    float* __restrict__ head_out, int head_kidx) {

    __shared__ __align__(16) float As[GBK][132];
    __shared__ __align__(16) float Ws[GBK][132];

    int M = cum[lvl];
    int ntiles = (M + GBM - 1) / GBM;
    int tid = threadIdx.x;
    int tx = tid & 15, ty = tid >> 4;
    int r0 = ty * 4;
    int c0 = tx * 4;

    for (int tile = blockIdx.x; tile < ntiles; tile += gridDim.x) {
        int row0 = tile * GBM;

        float acc[2][2][4][4];
#pragma unroll
        for (int p = 0; p < 2; ++p)
#pragma unroll
            for (int q = 0; q < 2; ++q)
#pragma unroll
                for (int i = 0; i < 4; ++i)
#pragma unroll
                    for (int j = 0; j < 4; ++j) acc[p][q][i][j] = 0.f;

        for (int ch = 0; ch < 8; ++ch) {
            const float* Asrc = (ch < 4) ? A1 : A2;
            const float* Wsrc = (ch < 4) ? W1 : W2;
            const int* gmap = (ch < 4) ? gatherA : gatherB;
            int kbase = (ch & 3) * GBK;

            // stage A: 128 rows x 32 k; m = idx&127 -> conflict-free LDS writes
#pragma unroll
            for (int it = 0; it < 4; ++it) {
                int idx = tid + it * 256;
                int m = idx & 127, kq = idx >> 7;
                int row = row0 + m;
                float4 v = make_float4(0.f, 0.f, 0.f, 0.f);
                if (row < M) {
                    int nr = order[row];
                    int ar = gmap ? gmap[nr] : nr;
                    v = *(const float4*)(Asrc + (size_t)ar * 128 + kbase + kq * 4);
                }
                As[kq * 4 + 0][m] = v.x;
                As[kq * 4 + 1][m] = v.y;
                As[kq * 4 + 2][m] = v.z;
                As[kq * 4 + 3][m] = v.w;
            }
            // stage W: 128 n x 32 k; n = idx>>3 -> coalesced global reads
#pragma unroll
            for (int it = 0; it < 4; ++it) {
                int idx = tid + it * 256;
                int n = idx >> 3, kq = idx & 7;
                float4 v = *(const float4*)(Wsrc + n * 128 + kbase + kq * 4);
                Ws[kq * 4 + 0][n] = v.x;
                Ws[kq * 4 + 1][n] = v.y;
                Ws[kq * 4 + 2][n] = v.z;
                Ws[kq * 4 + 3][n] = v.w;
            }
            __syncthreads();

#pragma unroll
            for (int kk = 0; kk < GBK; ++kk) {
                float4 a0 = *(const float4*)&As[kk][r0];
                float4 a1 = *(const float4*)&As[kk][r0 + 64];
                float4 w0 = *(const float4*)&Ws[kk][c0];
                float4 w1 = *(const float4*)&Ws[kk][c0 + 64];
                float av[2][4] = {{a0.x, a0.y, a0.z, a0.w}, {a1.x, a1.y, a1.z, a1.w}};
                float wv[2][4] = {{w0.x, w0.y, w0.z, w0.w}, {w1.x, w1.y, w1.z, w1.w}};
#pragma unroll
                for (int p = 0; p < 2; ++p)
#pragma unroll
                    for (int q = 0; q < 2; ++q)
#pragma unroll
                        for (int i = 0; i < 4; ++i)
#pragma unroll
                            for (int j = 0; j < 4; ++j)
                                acc[p][q][i][j] = fmaf(av[p][i], wv[q][j], acc[p][q][i][j]);
            }
            __syncthreads();
        }

#pragma unroll
        for (int p = 0; p < 2; ++p) {
#pragma unroll
            for (int i = 0; i < 4; ++i) {
                int row = row0 + p * 64 + r0 + i;
                if (row >= M) continue;
                int nr = order[row];
                float4 o0, o1;
                o0.x = fmaxf(acc[p][0][i][0] + bias[c0 + 0], 0.f);
                o0.y = fmaxf(acc[p][0][i][1] + bias[c0 + 1], 0.f);
                o0.z = fmaxf(acc[p][0][i][2] + bias[c0 + 2], 0.f);
                o0.w = fmaxf(acc[p][0][i][3] + bias[c0 + 3], 0.f);
                o1.x = fmaxf(acc[p][1][i][0] + bias[c0 + 64], 0.f);
                o1.y = fmaxf(acc[p][1][i][1] + bias[c0 + 65], 0.f);
                o1.z = fmaxf(acc[p][1][i][2] + bias[c0 + 66], 0.f);
                o1.w = fmaxf(acc[p][1][i][3] + bias[c0 + 67], 0.f);
                *(float4*)(Out + (size_t)nr * 128 + c0) = o0;
                *(float4*)(Out + (size_t)nr * 128 + c0 + 64) = o1;
            }
        }

        // fused head: tile 0 computed rows 0,1 (= nodes 0,1) fully
        if (tile == 0 && head_kidx >= 0) {
            dev_head(Out, W_e1, b_e1, W_e2, b_e2, W_h1, b_h1, W_h2, b_h2,
                     head_out, head_kidx);
        }
    }
}

// ---------------- finalize ----------------

__global__ void finalize(const float* __restrict__ head_out, float* __restrict__ out) {
    if (threadIdx.x == 0 && blockIdx.x == 0) {
        float a[LMAX];
        float p_not = 1.f, s = 0.f;
        for (int k = 0; k < LMAX; ++k) {
            float p = head_out[2 * k + 1];
            a[k] = p * p_not;
            p_not *= (1.f - p);
            s += a[k];
        }
        float inv = 1.f / (s + 1e-8f);
        float fs = 0.f, ed = 0.f;
        for (int k = 0; k < LMAX; ++k) {
            float al = a[k] * inv;
            out[2 + k] = al;
            fs += al * head_out[2 * k];
            ed += al * (float)(k + 1);
        }
        out[0] = fs;
        out[1] = ed;
    }
}

// ---------------- launch ----------------

extern "C" void kernel_launch(void* const* d_in, const int* in_sizes, int n_in,
                              void* d_out, int out_size, void* d_ws, size_t ws_size,
                              hipStream_t stream) {
    const float* x_full = (const float*)d_in[0];
    const float* W_in  = (const float*)d_in[1];
    const float* b_in  = (const float*)d_in[2];
    const float* W_l   = (const float*)d_in[3];
    const float* b_l   = (const float*)d_in[4];
    const float* W_r   = (const float*)d_in[5];
    const float* W_e1  = (const float*)d_in[6];
    const float* b_e1  = (const float*)d_in[7];
    const float* W_e2  = (const float*)d_in[8];
    const float* b_e2  = (const float*)d_in[9];
    const float* W_h1  = (const float*)d_in[10];
    const float* b_h1  = (const float*)d_in[11];
    const float* W_h2  = (const float*)d_in[12];
    const float* b_h2  = (const float*)d_in[13];
    const int* subset  = (const int*)d_in[14];
    const int* edge    = (const int*)d_in[15];
    const int* esrc = edge;
    const int* edst = edge + E_NUM;

    // workspace carve-up
    char* w = (char*)d_ws;
    float* HA = (float*)w;      w += (size_t)N_SUB * HD * 4;               // 41 MB
    float* HB = (float*)w;      w += (size_t)N_SUB * HD * 4;               // 41 MB
    int* cnt = (int*)w;         w += (size_t)N_SUB * 4;
    int* csr = (int*)w;         w += (size_t)N_SUB * CSR_STRIDE * 4;       // 20.5 MB
    int* level = (int*)w;       w += (size_t)N_SUB * 4;
    int* order = (int*)w;       w += (size_t)N_SUB * 4;
    int* bhist = (int*)w;       w += (size_t)(NB_SCAN + 1) * 8 * 4;
    int* lvlbase = (int*)w;     w += 64;
    int* cum = (int*)w;         w += 64;
    float* Wc1 = (float*)w;     w += 128 * 128 * 4;
    float* Wc2 = (float*)w;     w += 128 * 128 * 4;
    float* bc = (float*)w;      w += 512;
    float* head_out = (float*)w; w += 256;

    // prep: CSR64 fill (+level init, +wcomb)
    hipMemsetAsync(cnt, 0, (size_t)N_SUB * 4, stream);
    fill_wcomb<<<NB_E + WCOMB_BLKS, 256, 0, stream>>>(
        esrc, edst, cnt, csr, level, W_l, W_r, W_in, b_in, b_l, Wc1, Wc2, bc);

    // reverse BFS levels 1..4 (frontier-sparse, multi-block)
    for (int t = 0; t < 4; ++t)
        bfs_csr<<<NB_SCAN, 256, 0, stream>>>(cnt, csr, level, t);

    // level compaction
    hist_levels<<<NB_SCAN, 256, 0, stream>>>(level, bhist);
    scan_hist<<<1, 64, 0, stream>>>(bhist, lvlbase, cum);
    emit_order<<<NB_SCAN, 256, 0, stream>>>(level, bhist, lvlbase, order);

    // k=1 on C_4 (linearity: aggregate raw x, combined weights), head kidx=0
    aggregate_list<<<2048, 256, 0, stream>>>(
        x_full, HB, cnt, csr, order, cum, 4, subset);
    gemm_list<<<256, 256, 0, stream>>>(
        HB, x_full, Wc1, Wc2, bc, HA, order, nullptr, subset, cum, 4,
        W_e1, b_e1, W_e2, b_e2, W_h1, b_h1, W_h2, b_h2, head_out, 0);

    // k=2 on C_3
    aggregate_list<<<64, 256, 0, stream>>>(
        HA, HB, cnt, csr, order, cum, 3, nullptr);
    gemm_list<<<32, 256, 0, stream>>>(
        HB, HA, W_l, W_r, b_l, HA, order, nullptr, nullptr, cum, 3,
        W_e1, b_e1, W_e2, b_e2, W_h1, b_h1, W_h2, b_h2, head_out, 1);

    // k=3 on C_2
    aggregate_list<<<16, 256, 0, stream>>>(
        HA, HB, cnt, csr, order, cum, 2, nullptr);
    gemm_list<<<2, 256, 0, stream>>>(
        HB, HA, W_l, W_r, b_l, HA, order, nullptr, nullptr, cum, 2,
        W_e1, b_e1, W_e2, b_e2, W_h1, b_h1, W_h2, b_h2, head_out, 2);

    // k=4 on C_1 (~22 nodes)
    aggregate_list<<<8, 256, 0, stream>>>(
        HA, HB, cnt, csr, order, cum, 1, nullptr);
    gemm_list<<<1, 256, 0, stream>>>(
        HB, HA, W_l, W_r, b_l, HA, order, nullptr, nullptr, cum, 1,
        W_e1, b_e1, W_e2, b_e2, W_h1, b_h1, W_h2, b_h2, head_out, 3);

    // k=5 on C_0 (2 nodes)
    aggregate_list<<<1, 256, 0, stream>>>(
        HA, HB, cnt, csr, order, cum, 0, nullptr);
    gemm_list<<<1, 256, 0, stream>>>(
        HB, HA, W_l, W_r, b_l, HA, order, nullptr, nullptr, cum, 0,
        W_e1, b_e1, W_e2, b_e2, W_h1, b_h1, W_h2, b_h2, head_out, 4);

    finalize<<<1, 1, 0, stream>>>(head_out, (float*)d_out);
}

// Round 12
// 487.418 us; speedup vs baseline: 1.0994x; 1.0610x over previous
//
#include <hip/hip_runtime.h>
#include <hip/hip_bf16.h>

#define N_FULL 200000
#define N_SUB  80000
#define E_NUM  800000
#define IN_DIM 128
#define HD     128
#define LMAX   5

#define NB_SCAN ((N_SUB + 255) / 256)   // 313
#define NB_E (E_NUM / 256)              // 3125
#define WCOMB_BLKS 128
#define CSR_STRIDE 64

// ---------------- fill fixed-stride CSR + level init + wcomb + seeds ----------------
// csr64[d*64 + p] = src, p = atomicAdd(cnt[d]) (deg stays in cnt).
// Wc1 = W_l@W_in, Wc2 = W_r@W_in, bc = (W_l+W_r)@b_in + b_l
// Seeds: order[0..1] = {0,1}, cum[0] = 2, ctrl[0] (queue tail) = 2.

__global__ __launch_bounds__(256) void fill_wcomb(
    const int* __restrict__ esrc, const int* __restrict__ edst,
    int* __restrict__ cnt, int* __restrict__ csr, int* __restrict__ level,
    const float* __restrict__ W_l, const float* __restrict__ W_r,
    const float* __restrict__ W_in, const float* __restrict__ b_in,
    const float* __restrict__ b_l,
    float* __restrict__ Wc1, float* __restrict__ Wc2, float* __restrict__ bc,
    int* __restrict__ order, int* __restrict__ cum, int* __restrict__ ctrl) {
    int b = blockIdx.x;
    int t = threadIdx.x;
    if (b < NB_E) {
        if (b < NB_SCAN) {
            int i = b * 256 + t;
            if (i < N_SUB) level[i] = (i < 2) ? 0 : 7;
        }
        int i = b * 256 + t;
        int d = edst[i];
        int p = atomicAdd(&cnt[d], 1);
        if (p < CSR_STRIDE) csr[d * CSR_STRIDE + p] = esrc[i];
    } else {
        if (b == NB_E && t == 0) {
            order[0] = 0; order[1] = 1;
            cum[0] = 2;
            ctrl[0] = 2;          // queue tail (done[] counters stay memset-0)
        }
        __shared__ float sf[256];
        int f = b - NB_E;                    // 0..127
        if (t < 128) sf[t] = W_l[f * 128 + t];
        else sf[t] = W_r[f * 128 + (t - 128)];
        __syncthreads();
        int c = t & 127, p = t >> 7;
        const float* wrow = p ? (sf + 128) : sf;
        float acc = 0.f;
#pragma unroll 8
        for (int j = 0; j < 128; ++j)
            acc = fmaf(wrow[j], W_in[j * 128 + c], acc);
        (p ? Wc2 : Wc1)[f * 128 + c] = acc;
        if (t < 64) {
            float pa = (sf[t] + sf[128 + t]) * b_in[t] +
                       (sf[t + 64] + sf[192 + t]) * b_in[t + 64];
            for (int off = 32; off; off >>= 1) pa += __shfl_down(pa, off);
            if (t == 0) bc[f] = pa + b_l[f];
        }
    }
}

// ---------------- frontier-queue BFS step (multi-block, wave-agg append) ----------------
// Frontier = order[fb..fe); claims level[u]: 7 -> t+1; appends u into order[].
// Last finishing block snapshots cum[t+1] = queue tail.

__global__ __launch_bounds__(256) void bfs_q(
    const int* __restrict__ cnt, const int* __restrict__ csr,
    int* __restrict__ level, int* __restrict__ order,
    int* __restrict__ cum, int* __restrict__ ctrl, int t) {
    int fb = (t == 0) ? 0 : cum[t - 1];
    int fe = cum[t];
    int lane = threadIdx.x & 63;
    int gw = blockIdx.x * 4 + (threadIdx.x >> 6);
    int nw = gridDim.x * 4;
    for (int fi = fb + gw; fi < fe; fi += nw) {
        int v = order[fi];
        int deg = cnt[v];
        if (deg > CSR_STRIDE) deg = CSR_STRIDE;
        bool succ = false;
        int u = -1;
        if (lane < deg) {
            u = csr[v * CSR_STRIDE + lane];
            if (level[u] == 7 && atomicMin(&level[u], t + 1) == 7) succ = true;
        }
        unsigned long long m = __ballot(succ);
        if (m) {
            int rank = (int)__popcll(m & ((1ull << lane) - 1ull));
            int leader = __ffsll((long long)m) - 1;
            int base = 0;
            if (lane == leader) base = atomicAdd(&ctrl[0], (int)__popcll(m));
            base = __shfl(base, leader);
            if (succ) order[base + rank] = u;
        }
    }
    __syncthreads();
    if (threadIdx.x == 0) {
        __threadfence();
        if (atomicAdd(&ctrl[1 + t], 1) == (int)gridDim.x - 1)
            cum[t + 1] = atomicAdd(&ctrl[0], 0);
    }
}

// ---------------- lvl-4 aggregate: compacted output + gsrc fill ----------------
// AGG[i][:] = mean over in-nbrs of order[i] of x_full[subset[nbr]]; gsrc[i]=subset[order[i]]

__global__ __launch_bounds__(256) void aggregate_c4(
    const float* __restrict__ x_full, float* __restrict__ AGG,
    int* __restrict__ gsrc,
    const int* __restrict__ cnt, const int* __restrict__ csr,
    const int* __restrict__ order, const int* __restrict__ cum,
    const int* __restrict__ subset) {
    int M = cum[4];
    int ngroups = (M + 3) >> 2;
    int wid = threadIdx.x >> 6, lane = threadIdx.x & 63;
    for (int g = blockIdx.x; g < ngroups; g += gridDim.x) {
        int ni = g * 4 + wid;
        if (ni >= M) continue;
        int node = order[ni];
        int deg = cnt[node];
        int cl = deg > CSR_STRIDE ? CSR_STRIDE : deg;
        int beg = node * CSR_STRIDE, end = beg + cl;
        float ax = 0.f, ay = 0.f, bx = 0.f, by = 0.f;
        int j = beg;
        for (; j + 1 < end; j += 2) {
            int r0 = subset[csr[j]];
            int r1 = subset[csr[j + 1]];
            float2 v0 = *(const float2*)(x_full + (size_t)r0 * HD + lane * 2);
            float2 v1 = *(const float2*)(x_full + (size_t)r1 * HD + lane * 2);
            ax += v0.x; ay += v0.y;
            bx += v1.x; by += v1.y;
        }
        if (j < end) {
            int r0 = subset[csr[j]];
            float2 v0 = *(const float2*)(x_full + (size_t)r0 * HD + lane * 2);
            ax += v0.x; ay += v0.y;
        }
        float inv = 1.0f / (float)(deg > 1 ? deg : 1);
        *(float2*)(AGG + (size_t)ni * HD + lane * 2) =
            make_float2((ax + bx) * inv, (ay + by) * inv);
        if (lane == 0 && wid == 0) { /* nothing */ }
        if (lane == 0) gsrc[ni] = subset[node];
    }
}

// ---------------- mean aggregation over node list (node-indexed, k>=2) ----------------

__global__ __launch_bounds__(256) void aggregate_list(
    const float* __restrict__ H, float* __restrict__ Out,
    const int* __restrict__ cnt, const int* __restrict__ csr,
    const int* __restrict__ order, const int* __restrict__ cum, int lvl) {
    int M = cum[lvl];
    int ngroups = (M + 3) >> 2;
    int wid = threadIdx.x >> 6, lane = threadIdx.x & 63;
    for (int g = blockIdx.x; g < ngroups; g += gridDim.x) {
        int ni = g * 4 + wid;
        if (ni >= M) continue;
        int node = order[ni];
        int deg = cnt[node];
        int cl = deg > CSR_STRIDE ? CSR_STRIDE : deg;
        int beg = node * CSR_STRIDE, end = beg + cl;
        float ax = 0.f, ay = 0.f, bx = 0.f, by = 0.f;
        int j = beg;
        for (; j + 1 < end; j += 2) {
            int s0 = csr[j], s1 = csr[j + 1];
            float2 v0 = *(const float2*)(H + (size_t)s0 * HD + lane * 2);
            float2 v1 = *(const float2*)(H + (size_t)s1 * HD + lane * 2);
            ax += v0.x; ay += v0.y;
            bx += v1.x; by += v1.y;
        }
        if (j < end) {
            int s0 = csr[j];
            float2 v0 = *(const float2*)(H + (size_t)s0 * HD + lane * 2);
            ax += v0.x; ay += v0.y;
        }
        float inv = 1.0f / (float)(deg > 1 ? deg : 1);
        *(float2*)(Out + (size_t)node * HD + lane * 2) =
            make_float2((ax + bx) * inv, (ay + by) * inv);
    }
}

// ---------------- head MLP on nodes 0,1 (device fn, 256 threads) ----------------

__device__ void dev_head(
    const float* __restrict__ H,
    const float* __restrict__ W_e1, const float* __restrict__ b_e1,
    const float* __restrict__ W_e2, const float* __restrict__ b_e2,
    const float* __restrict__ W_h1, const float* __restrict__ b_h1,
    const float* __restrict__ W_h2, const float* __restrict__ b_h2,
    float* __restrict__ head_out, int kidx) {

    __shared__ float feat[384];
    __shared__ float rowo[128];
    __shared__ float sc_sh;
    int t = threadIdx.x, lane = t & 63, wv = t >> 6;

    __syncthreads();
    if (t < 128) {
        float a = H[t], b = H[128 + t];
        feat[t] = a;
        feat[128 + t] = b;
        feat[256 + t] = a * b;
    }
    __syncthreads();

    for (int r = wv; r < 128; r += 4) {
        const float* wr = W_e1 + r * 384;
        float acc = 0.f;
#pragma unroll
        for (int j = 0; j < 6; ++j)
            acc += feat[lane + 64 * j] * wr[lane + 64 * j];
        for (int off = 32; off; off >>= 1) acc += __shfl_down(acc, off);
        if (lane == 0) rowo[r] = fmaxf(acc + b_e1[r], 0.f) * W_e2[r];
    }
    __syncthreads();
    if (wv == 0) {
        float v = rowo[lane] + rowo[lane + 64];
        for (int off = 32; off; off >>= 1) v += __shfl_down(v, off);
        if (lane == 0) sc_sh = v + b_e2[0];
    }
    __syncthreads();
    float score = sc_sh;

    for (int r = wv; r < 64; r += 4) {
        const float* wh = W_h1 + r * 257;
        float acc = 0.f;
#pragma unroll
        for (int j = 0; j < 4; ++j)
            acc += feat[lane + 64 * j] * wh[lane + 64 * j];
        if (lane == 0) acc += score * wh[256];
        for (int off = 32; off; off >>= 1) acc += __shfl_down(acc, off);
        if (lane == 0) rowo[r] = fmaxf(acc + b_h1[r], 0.f) * W_h2[r];
    }
    __syncthreads();
    if (wv == 0) {
        float v = rowo[lane];
        for (int off = 32; off; off >>= 1) v += __shfl_down(v, off);
        if (lane == 0) {
            float p = 1.f / (1.f + expf(-(v + b_h2[0])));
            head_out[kidx * 2 + 0] = score;
            head_out[kidx * 2 + 1] = p;
        }
    }
    __syncthreads();
}

// ---------------- step-1 GEMM: sequential A, register double-buffered staging ----------
// rows i < M: A1 = AGG[i] (sequential), A2 = x_full[gsrc[i]] (1-hop gather).
// HA[order[i]][:] = relu(A1 @ W1.T + A2 @ W2.T + bias). Fused head kidx=0 on tile 0.

#define GBM 128
#define GBK 32

__global__ __launch_bounds__(256) void gemm_seq(
    const float* __restrict__ AGG, const float* __restrict__ x_full,
    const int* __restrict__ gsrc,
    const float* __restrict__ W1, const float* __restrict__ W2,
    const float* __restrict__ bias, float* __restrict__ HA,
    const int* __restrict__ order, const int* __restrict__ cum,
    const float* __restrict__ W_e1, const float* __restrict__ b_e1,
    const float* __restrict__ W_e2, const float* __restrict__ b_e2,
    const float* __restrict__ W_h1, const float* __restrict__ b_h1,
    const float* __restrict__ W_h2, const float* __restrict__ b_h2,
    float* __restrict__ head_out) {

    __shared__ __align__(16) float As[GBK][132];
    __shared__ __align__(16) float Ws[GBK][132];

    int M = cum[4];
    int ntiles = (M + GBM - 1) / GBM;
    int tid = threadIdx.x;
    int tx = tid & 15, ty = tid >> 4;
    int r0 = ty * 4;
    int c0 = tx * 4;

    for (int tile = blockIdx.x; tile < ntiles; tile += gridDim.x) {
        int row0 = tile * GBM;

        float acc[2][2][4][4];
#pragma unroll
        for (int p = 0; p < 2; ++p)
#pragma unroll
            for (int q = 0; q < 2; ++q)
#pragma unroll
                for (int i = 0; i < 4; ++i)
#pragma unroll
                    for (int j = 0; j < 4; ++j) acc[p][q][i][j] = 0.f;

        float4 ra0, ra1, ra2, ra3, rw0, rw1, rw2, rw3;

#define LOADCH(CH)                                                              \
        {                                                                       \
            int ch_ = (CH);                                                     \
            const float* Wsrc_ = (ch_ < 4) ? W1 : W2;                           \
            int kbase_ = (ch_ & 3) * GBK;                                       \
            _Pragma("unroll")                                                   \
            for (int it = 0; it < 4; ++it) {                                    \
                int idx = tid + it * 256;                                       \
                int m = idx & 127, kq = idx >> 7;                               \
                int row = row0 + m;                                             \
                float4 v = make_float4(0.f, 0.f, 0.f, 0.f);                     \
                if (row < M) {                                                  \
                    if (ch_ < 4)                                                \
                        v = *(const float4*)(AGG + (size_t)row * 128 + kbase_ + kq * 4); \
                    else {                                                      \
                        int ar = gsrc[row];                                     \
                        v = *(const float4*)(x_full + (size_t)ar * 128 + kbase_ + kq * 4); \
                    }                                                           \
                }                                                               \
                if (it == 0) ra0 = v; else if (it == 1) ra1 = v;                \
                else if (it == 2) ra2 = v; else ra3 = v;                        \
            }                                                                   \
            _Pragma("unroll")                                                   \
            for (int it = 0; it < 4; ++it) {                                    \
                int idx = tid + it * 256;                                       \
                int n = idx >> 3, kq = idx & 7;                                 \
                float4 v = *(const float4*)(Wsrc_ + n * 128 + kbase_ + kq * 4); \
                if (it == 0) rw0 = v; else if (it == 1) rw1 = v;                \
                else if (it == 2) rw2 = v; else rw3 = v;                        \
            }                                                                   \
        }

        LOADCH(0);
        for (int ch = 0; ch < 8; ++ch) {
            __syncthreads();   // previous chunk's LDS consumers done
            // regs -> LDS
#pragma unroll
            for (int it = 0; it < 4; ++it) {
                int idx = tid + it * 256;
                int m = idx & 127, kq = idx >> 7;
                float4 v = (it == 0) ? ra0 : (it == 1) ? ra1 : (it == 2) ? ra2 : ra3;
                As[kq * 4 + 0][m] = v.x;
                As[kq * 4 + 1][m] = v.y;
                As[kq * 4 + 2][m] = v.z;
                As[kq * 4 + 3][m] = v.w;
            }
#pragma unroll
            for (int it = 0; it < 4; ++it) {
                int idx = tid + it * 256;
                int n = idx >> 3, kq = idx & 7;
                float4 v = (it == 0) ? rw0 : (it == 1) ? rw1 : (it == 2) ? rw2 : rw3;
                Ws[kq * 4 + 0][n] = v.x;
                Ws[kq * 4 + 1][n] = v.y;
                Ws[kq * 4 + 2][n] = v.z;
                Ws[kq * 4 + 3][n] = v.w;
            }
            __syncthreads();
            if (ch < 7) LOADCH(ch + 1);   // issue next chunk; hides under compute

#pragma unroll
            for (int kk = 0; kk < GBK; ++kk) {
                float4 a0 = *(const float4*)&As[kk][r0];
                float4 a1 = *(const float4*)&As[kk][r0 + 64];
                float4 w0 = *(const float4*)&Ws[kk][c0];
                float4 w1 = *(const float4*)&Ws[kk][c0 + 64];
                float av[2][4] = {{a0.x, a0.y, a0.z, a0.w}, {a1.x, a1.y, a1.z, a1.w}};
                float wv[2][4] = {{w0.x, w0.y, w0.z, w0.w}, {w1.x, w1.y, w1.z, w1.w}};
#pragma unroll
                for (int p = 0; p < 2; ++p)
#pragma unroll
                    for (int q = 0; q < 2; ++q)
#pragma unroll
                        for (int i = 0; i < 4; ++i)
#pragma unroll
                            for (int j = 0; j < 4; ++j)
                                acc[p][q][i][j] = fmaf(av[p][i], wv[q][j], acc[p][q][i][j]);
            }
        }
#undef LOADCH

#pragma unroll
        for (int p = 0; p < 2; ++p) {
#pragma unroll
            for (int i = 0; i < 4; ++i) {
                int row = row0 + p * 64 + r0 + i;
                if (row >= M) continue;
                int nr = order[row];
                float4 o0, o1;
                o0.x = fmaxf(acc[p][0][i][0] + bias[c0 + 0], 0.f);
                o0.y = fmaxf(acc[p][0][i][1] + bias[c0 + 1], 0.f);
                o0.z = fmaxf(acc[p][0][i][2] + bias[c0 + 2], 0.f);
                o0.w = fmaxf(acc[p][0][i][3] + bias[c0 + 3], 0.f);
                o1.x = fmaxf(acc[p][1][i][0] + bias[c0 + 64], 0.f);
                o1.y = fmaxf(acc[p][1][i][1] + bias[c0 + 65], 0.f);
                o1.z = fmaxf(acc[p][1][i][2] + bias[c0 + 66], 0.f);
                o1.w = fmaxf(acc[p][1][i][3] + bias[c0 + 67], 0.f);
                *(float4*)(HA + (size_t)nr * 128 + c0) = o0;
                *(float4*)(HA + (size_t)nr * 128 + c0 + 64) = o1;
            }
        }

        if (tile == 0) {
            dev_head(HA, W_e1, b_e1, W_e2, b_e2, W_h1, b_h1, W_h2, b_h2,
                     head_out, 0);
        }
    }
}

// ---------------- gathered GEMM for k>=2 (small M) ----------------

__global__ __launch_bounds__(256) void gemm_list(
    const float* __restrict__ A1, const float* __restrict__ A2,
    const float* __restrict__ W1, const float* __restrict__ W2,
    const float* __restrict__ bias, float* __restrict__ Out,
    const int* __restrict__ order, const int* __restrict__ cum, int lvl,
    const float* __restrict__ W_e1, const float* __restrict__ b_e1,
    const float* __restrict__ W_e2, const float* __restrict__ b_e2,
    const float* __restrict__ W_h1, const float* __restrict__ b_h1,
    const float* __restrict__ W_h2, const float* __restrict__ b_h2,
    float* __restrict__ head_out, int head_kidx) {

    __shared__ __align__(16) float As[GBK][132];
    __shared__ __align__(16) float Ws[GBK][132];

    int M = cum[lvl];
    int ntiles = (M + GBM - 1) / GBM;
    int tid = threadIdx.x;
    int tx = tid & 15, ty = tid >> 4;
    int r0 = ty * 4;
    int c0 = tx * 4;

    for (int tile = blockIdx.x; tile < ntiles; tile += gridDim.x) {
        int row0 = tile * GBM;

        float acc[2][2][4][4];
#pragma unroll
        for (int p = 0; p < 2; ++p)
#pragma unroll
            for (int q = 0; q < 2; ++q)
#pragma unroll
                for (int i = 0; i < 4; ++i)
#pragma unroll
                    for (int j = 0; j < 4; ++j) acc[p][q][i][j] = 0.f;

        for (int ch = 0; ch < 8; ++ch) {
            const float* Asrc = (ch < 4) ? A1 : A2;
            const float* Wsrc = (ch < 4) ? W1 : W2;
            int kbase = (ch & 3) * GBK;

#pragma unroll
            for (int it = 0; it < 4; ++it) {
                int idx = tid + it * 256;
                int m = idx & 127, kq = idx >> 7;
                int row = row0 + m;
                float4 v = make_float4(0.f, 0.f, 0.f, 0.f);
                if (row < M) {
                    int ar = order[row];
                    v = *(const float4*)(Asrc + (size_t)ar * 128 + kbase + kq * 4);
                }
                As[kq * 4 + 0][m] = v.x;
                As[kq * 4 + 1][m] = v.y;
                As[kq * 4 + 2][m] = v.z;
                As[kq * 4 + 3][m] = v.w;
            }
#pragma unroll
            for (int it = 0; it < 4; ++it) {
                int idx = tid + it * 256;
                int n = idx >> 3, kq = idx & 7;
                float4 v = *(const float4*)(Wsrc + n * 128 + kbase + kq * 4);
                Ws[kq * 4 + 0][n] = v.x;
                Ws[kq * 4 + 1][n] = v.y;
                Ws[kq * 4 + 2][n] = v.z;
                Ws[kq * 4 + 3][n] = v.w;
            }
            __syncthreads();

#pragma unroll
            for (int kk = 0; kk < GBK; ++kk) {
                float4 a0 = *(const float4*)&As[kk][r0];
                float4 a1 = *(const float4*)&As[kk][r0 + 64];
                float4 w0 = *(const float4*)&Ws[kk][c0];
                float4 w1 = *(const float4*)&Ws[kk][c0 + 64];
                float av[2][4] = {{a0.x, a0.y, a0.z, a0.w}, {a1.x, a1.y, a1.z, a1.w}};
                float wv[2][4] = {{w0.x, w0.y, w0.z, w0.w}, {w1.x, w1.y, w1.z, w1.w}};
#pragma unroll
                for (int p = 0; p < 2; ++p)
#pragma unroll
                    for (int q = 0; q < 2; ++q)
#pragma unroll
                        for (int i = 0; i < 4; ++i)
#pragma unroll
                            for (int j = 0; j < 4; ++j)
                                acc[p][q][i][j] = fmaf(av[p][i], wv[q][j], acc[p][q][i][j]);
            }
            __syncthreads();
        }

#pragma unroll
        for (int p = 0; p < 2; ++p) {
#pragma unroll
            for (int i = 0; i < 4; ++i) {
                int row = row0 + p * 64 + r0 + i;
                if (row >= M) continue;
                int nr = order[row];
                float4 o0, o1;
                o0.x = fmaxf(acc[p][0][i][0] + bias[c0 + 0], 0.f);
                o0.y = fmaxf(acc[p][0][i][1] + bias[c0 + 1], 0.f);
                o0.z = fmaxf(acc[p][0][i][2] + bias[c0 + 2], 0.f);
                o0.w = fmaxf(acc[p][0][i][3] + bias[c0 + 3], 0.f);
                o1.x = fmaxf(acc[p][1][i][0] + bias[c0 + 64], 0.f);
                o1.y = fmaxf(acc[p][1][i][1] + bias[c0 + 65], 0.f);
                o1.z = fmaxf(acc[p][1][i][2] + bias[c0 + 66], 0.f);
                o1.w = fmaxf(acc[p][1][i][3] + bias[c0 + 67], 0.f);
                *(float4*)(Out + (size_t)nr * 128 + c0) = o0;
                *(float4*)(Out + (size_t)nr * 128 + c0 + 64) = o1;
            }
        }

        if (tile == 0 && head_kidx >= 0) {
            dev_head(Out, W_e1, b_e1, W_e2, b_e2, W_h1, b_h1, W_h2, b_h2,
                     head_out, head_kidx);
        }
    }
}

// ---------------- finalize ----------------

__global__ void finalize(const float* __restrict__ head_out, float* __restrict__ out) {
    if (threadIdx.x == 0 && blockIdx.x == 0) {
        float a[LMAX];
        float p_not = 1.f, s = 0.f;
        for (int k = 0; k < LMAX; ++k) {
            float p = head_out[2 * k + 1];
            a[k] = p * p_not;
            p_not *= (1.f - p);
            s += a[k];
        }
        float inv = 1.f / (s + 1e-8f);
        float fs = 0.f, ed = 0.f;
        for (int k = 0; k < LMAX; ++k) {
            float al = a[k] * inv;
            out[2 + k] = al;
            fs += al * head_out[2 * k];
            ed += al * (float)(k + 1);
        }
        out[0] = fs;
        out[1] = ed;
    }
}

// ---------------- launch ----------------

extern "C" void kernel_launch(void* const* d_in, const int* in_sizes, int n_in,
                              void* d_out, int out_size, void* d_ws, size_t ws_size,
                              hipStream_t stream) {
    const float* x_full = (const float*)d_in[0];
    const float* W_in  = (const float*)d_in[1];
    const float* b_in  = (const float*)d_in[2];
    const float* W_l   = (const float*)d_in[3];
    const float* b_l   = (const float*)d_in[4];
    const float* W_r   = (const float*)d_in[5];
    const float* W_e1  = (const float*)d_in[6];
    const float* b_e1  = (const float*)d_in[7];
    const float* W_e2  = (const float*)d_in[8];
    const float* b_e2  = (const float*)d_in[9];
    const float* W_h1  = (const float*)d_in[10];
    const float* b_h1  = (const float*)d_in[11];
    const float* W_h2  = (const float*)d_in[12];
    const float* b_h2  = (const float*)d_in[13];
    const int* subset  = (const int*)d_in[14];
    const int* edge    = (const int*)d_in[15];
    const int* esrc = edge;
    const int* edst = edge + E_NUM;

    // workspace carve-up
    char* w = (char*)d_ws;
    float* HA = (float*)w;      w += (size_t)N_SUB * HD * 4;               // 41 MB
    float* HB = (float*)w;      w += (size_t)N_SUB * HD * 4;               // 41 MB (AGG compact / k>=2 agg)
    int* cnt = (int*)w;         w += (size_t)N_SUB * 4;
    int* ctrl = (int*)w;        w += 256;                                  // queue tail + done[]
    int* csr = (int*)w;         w += (size_t)N_SUB * CSR_STRIDE * 4;       // 20.5 MB
    int* level = (int*)w;       w += (size_t)N_SUB * 4;
    int* order = (int*)w;       w += (size_t)N_SUB * 4;
    int* gsrc = (int*)w;        w += (size_t)N_SUB * 4;
    int* cum = (int*)w;         w += 64;
    float* Wc1 = (float*)w;     w += 128 * 128 * 4;
    float* Wc2 = (float*)w;     w += 128 * 128 * 4;
    float* bc = (float*)w;      w += 512;
    float* head_out = (float*)w; w += 256;

    // prep: zero cnt + ctrl, fill CSR64 (+level init, +wcomb, +queue seeds)
    hipMemsetAsync(cnt, 0, (size_t)N_SUB * 4 + 256, stream);
    fill_wcomb<<<NB_E + WCOMB_BLKS, 256, 0, stream>>>(
        esrc, edst, cnt, csr, level, W_l, W_r, W_in, b_in, b_l,
        Wc1, Wc2, bc, order, cum, ctrl);

    // frontier-queue BFS levels 1..4 (builds order[] + cum[] directly)
    for (int t = 0; t < 4; ++t)
        bfs_q<<<32, 256, 0, stream>>>(cnt, csr, level, order, cum, ctrl, t);

    // k=1 on C_4: compacted aggregate + sequential GEMM (linearity), head 0
    aggregate_c4<<<2048, 256, 0, stream>>>(
        x_full, HB, gsrc, cnt, csr, order, cum, subset);
    gemm_seq<<<256, 256, 0, stream>>>(
        HB, x_full, gsrc, Wc1, Wc2, bc, HA, order, cum,
        W_e1, b_e1, W_e2, b_e2, W_h1, b_h1, W_h2, b_h2, head_out);

    // k=2 on C_3
    aggregate_list<<<64, 256, 0, stream>>>(HA, HB, cnt, csr, order, cum, 3);
    gemm_list<<<32, 256, 0, stream>>>(
        HB, HA, W_l, W_r, b_l, HA, order, cum, 3,
        W_e1, b_e1, W_e2, b_e2, W_h1, b_h1, W_h2, b_h2, head_out, 1);

    // k=3 on C_2
    aggregate_list<<<16, 256, 0, stream>>>(HA, HB, cnt, csr, order, cum, 2);
    gemm_list<<<2, 256, 0, stream>>>(
        HB, HA, W_l, W_r, b_l, HA, order, cum, 2,
        W_e1, b_e1, W_e2, b_e2, W_h1, b_h1, W_h2, b_h2, head_out, 2);

    // k=4 on C_1 (~22 nodes)
    aggregate_list<<<8, 256, 0, stream>>>(HA, HB, cnt, csr, order, cum, 1);
    gemm_list<<<1, 256, 0, stream>>>(
        HB, HA, W_l, W_r, b_l, HA, order, cum, 1,
        W_e1, b_e1, W_e2, b_e2, W_h1, b_h1, W_h2, b_h2, head_out, 3);

    // k=5 on C_0 (2 nodes)
    aggregate_list<<<1, 256, 0, stream>>>(HA, HB, cnt, csr, order, cum, 0);
    gemm_list<<<1, 256, 0, stream>>>(
        HB, HA, W_l, W_r, b_l, HA, order, cum, 0,
        W_e1, b_e1, W_e2, b_e2, W_h1, b_h1, W_h2, b_h2, head_out, 4);

    finalize<<<1, 1, 0, stream>>>(head_out, (float*)d_out);
}